// Round 2
// baseline (1171.372 us; speedup 1.0000x reference)
//
#include <hip/hip_runtime.h>
#include <math.h>

#define B_   256
#define L_   196
#define R_   1024
#define E_   1024
#define H_   512
#define G4R  4096   // 4*R
#define DIN  3072   // E + 2R

typedef short v4s __attribute__((ext_vector_type(4)));
typedef short v8s __attribute__((ext_vector_type(8)));
typedef float v4f __attribute__((ext_vector_type(4)));

__device__ __forceinline__ float sigmoidf_(float x) {
    return 1.0f / (1.0f + __expf(-x));
}
__device__ __forceinline__ float tanhf_(float x) {
    float ax = fabsf(x);
    float t  = __expf(-2.0f * ax);
    float r  = (1.0f - t) / (1.0f + t);
    return copysignf(r, x);
}

// split fp32 into two truncated bf16 parts: x ~= hi + lo (error ~2^-14 rel)
__device__ __forceinline__ void split2(float x, short& hi, short& lo) {
    unsigned u = __float_as_uint(x);
    hi = (short)(u >> 16);
    float r = x - __uint_as_float(u & 0xFFFF0000u);
    lo = (short)(__float_as_uint(r) >> 16);
}

__device__ __forceinline__ void fma4(float4& a, float s, const float4& v) {
    a.x += s * v.x; a.y += s * v.y; a.z += s * v.z; a.w += s * v.w;
}

// ============================================================================
// Split-K MFMA GEMM over up to 4 K-segments (1024 each).
//   C_part[kc] (B x N tile) = sum over this block's K-range of Aseg @ Wseg^T
// MT x MT tile (MT=64: wave tile 32x32; MT=32: wave tile 16x16), BK=32,
// double-buffered LDS (40960B / 20480B -> 4 / 8 blocks-per-CU LDS-fit),
// register-staged prefetch, bijective XCD swizzle.
// Split-precision bf16 (3 mfma per frag pair) ~ fp32 accuracy.
// grid.x = mTiles * nTiles * KS ; tile i is a BK=32 slice; seg = (i>>5)&3.
// Bias added only by kc==0 blocks.
// ============================================================================
template<int MT>
__global__ __launch_bounds__(256, 4) void gemm_sk(
    const float* __restrict__ a0, int lda0,
    const float* __restrict__ a1, int lda1,
    const float* __restrict__ a2, int lda2,
    const float* __restrict__ a3, int lda3,
    const float* __restrict__ w0, int ldw0,
    const float* __restrict__ w1, int ldw1,
    const float* __restrict__ w2, int ldw2,
    const float* __restrict__ w3, int ldw3,
    const float* __restrict__ bias1, const float* __restrict__ bias2,
    float* __restrict__ C, int N,
    int lgM, int KSm1, int lgKS, int nt)
{
    constexpr int FM = MT / 32;   // frags per wave dim (64->2, 32->1)
    constexpr int CH = MT / 32;   // staged float4 chunks per thread

    // row pad 40 shorts: frag-read bank = (20r + 4q) mod 32 -> only r/r+8 alias (2-way, free)
    __shared__ alignas(16) short lds[2][4][MT][40];

    const int t     = threadIdx.x;
    const int lane  = t & 63;
    const int wave  = t >> 6;
    const int waveM = wave & 1;
    const int waveN = wave >> 1;
    const int l16   = lane & 15;
    const int quad  = lane >> 4;

    // XCD swizzle: consecutive-on-XCD wg ids; groups of mTiles share a W panel.
    const int bid = blockIdx.x;
    const int wg  = (bid & 7) * (gridDim.x >> 3) + (bid >> 3);
    const int m    = wg & ((1 << lgM) - 1);
    const int rest = wg >> lgM;
    const int kc   = rest & KSm1;
    const int n    = rest >> lgKS;
    const int mBase = m * MT;
    const int nBase = n * MT;
    const int t0    = kc * nt;     // first global k-tile for this block

    const int rowA = t >> 3;          // 0..31
    const int kkA  = (t & 7) * 4;     // k offset (floats) within BK=32

    v4f acc[FM][FM] = {};

    auto loadT = [&](int i, float4* RA, float4* RW) {
        const int s  = (i >> 5) & 3;
        const int k0 = (i & 31) << 5;
        const float* pa = (s == 0) ? a0 : (s == 1) ? a1 : (s == 2) ? a2 : a3;
        const int    la = (s == 0) ? lda0 : (s == 1) ? lda1 : (s == 2) ? lda2 : lda3;
        const float* pw = (s == 0) ? w0 : (s == 1) ? w1 : (s == 2) ? w2 : w3;
        const int    lw = (s == 0) ? ldw0 : (s == 1) ? ldw1 : (s == 2) ? ldw2 : ldw3;
        pa += (size_t)(mBase + rowA) * la + k0 + kkA;
        pw += (size_t)(nBase + rowA) * lw + k0 + kkA;
#pragma unroll
        for (int c = 0; c < CH; ++c) {
            RA[c] = *(const float4*)(pa + (size_t)(c * 32) * la);
            RW[c] = *(const float4*)(pw + (size_t)(c * 32) * lw);
        }
    };

    auto storeT = [&](int buf, const float4* RA, const float4* RW) {
#pragma unroll
        for (int c = 0; c < CH; ++c) {
            const int row = rowA + c * 32;
            short h0, h1, h2, h3, l0, l1, l2, l3;
            split2(RA[c].x, h0, l0); split2(RA[c].y, h1, l1);
            split2(RA[c].z, h2, l2); split2(RA[c].w, h3, l3);
            v4s hv = { h0, h1, h2, h3 };
            v4s lv = { l0, l1, l2, l3 };
            *(v4s*)&lds[buf][0][row][kkA] = hv;
            *(v4s*)&lds[buf][1][row][kkA] = lv;
            split2(RW[c].x, h0, l0); split2(RW[c].y, h1, l1);
            split2(RW[c].z, h2, l2); split2(RW[c].w, h3, l3);
            v4s hw = { h0, h1, h2, h3 };
            v4s lw = { l0, l1, l2, l3 };
            *(v4s*)&lds[buf][2][row][kkA] = hw;
            *(v4s*)&lds[buf][3][row][kkA] = lw;
        }
    };

    auto compT = [&](int buf) {
        v8s ah[FM], al[FM], wh[FM], wl[FM];
#pragma unroll
        for (int fi = 0; fi < FM; ++fi) {
            int r = waveM * (MT / 2) + fi * 16 + l16;
            ah[fi] = *(const v8s*)&lds[buf][0][r][quad * 8];
            al[fi] = *(const v8s*)&lds[buf][1][r][quad * 8];
        }
#pragma unroll
        for (int fj = 0; fj < FM; ++fj) {
            int r = waveN * (MT / 2) + fj * 16 + l16;
            wh[fj] = *(const v8s*)&lds[buf][2][r][quad * 8];
            wl[fj] = *(const v8s*)&lds[buf][3][r][quad * 8];
        }
#pragma unroll
        for (int fi = 0; fi < FM; ++fi)
#pragma unroll
            for (int fj = 0; fj < FM; ++fj) {
                acc[fi][fj] = __builtin_amdgcn_mfma_f32_16x16x32_bf16(
                    al[fi], wh[fj], acc[fi][fj], 0, 0, 0);
                acc[fi][fj] = __builtin_amdgcn_mfma_f32_16x16x32_bf16(
                    ah[fi], wl[fj], acc[fi][fj], 0, 0, 0);
                acc[fi][fj] = __builtin_amdgcn_mfma_f32_16x16x32_bf16(
                    ah[fi], wh[fj], acc[fi][fj], 0, 0, 0);
            }
    };

    float4 rA0[CH], rW0[CH], rA1[CH], rW1[CH];
    loadT(t0, rA0, rW0);

#pragma unroll 1
    for (int i = 0; i < nt; i += 2) {
        storeT(0, rA0, rW0);
        loadT(t0 + i + 1, rA1, rW1);       // in flight across barrier+compute
        __syncthreads();
        compT(0);
        storeT(1, rA1, rW1);
        if (i + 2 < nt) loadT(t0 + i + 2, rA0, rW0);
        __syncthreads();
        compT(1);
    }

    // epilogue: C/D layout col=lane&15, row=quad*4+reg
    float* Cp = C + (size_t)kc * B_ * N;
#pragma unroll
    for (int fj = 0; fj < FM; ++fj) {
        int nn = nBase + waveN * (MT / 2) + fj * 16 + l16;
        float bb = 0.0f;
        if (kc == 0 && bias1) bb = bias1[nn] + (bias2 ? bias2[nn] : 0.0f);
#pragma unroll
        for (int fi = 0; fi < FM; ++fi) {
            int m0 = mBase + waveM * (MT / 2) + fi * 16 + quad * 4;
#pragma unroll
            for (int r = 0; r < 4; ++r)
                Cp[(size_t)(m0 + r) * N + nn] = acc[fi][fj][r] + bb;
        }
    }
}

// gates partials (nparts x B x 4R) + c_in (B,R) -> h_out, c_out; optional mirror of h.
__global__ __launch_bounds__(256) void lstm_cell(
    const float* __restrict__ gp, int nparts,
    const float* __restrict__ c_in,
    float* __restrict__ h_out, float* __restrict__ c_out,
    float* __restrict__ h_out2)
{
    int e = blockIdx.x * 256 + threadIdx.x;
    int b = e >> 10;
    int j = e & 1023;
    float s0 = 0, s1 = 0, s2 = 0, s3 = 0;
    for (int p = 0; p < nparts; ++p) {
        const float* g = gp + (size_t)p * B_ * G4R + (size_t)b * G4R;
        s0 += g[j];
        s1 += g[j + 1024];
        s2 += g[j + 2048];
        s3 += g[j + 3072];
    }
    float i_ = sigmoidf_(s0);
    float f_ = sigmoidf_(s1);
    float gg = tanhf_(s2);
    float o_ = sigmoidf_(s3);
    float c  = f_ * c_in[e] + i_ * gg;
    float h  = o_ * tanhf_(c);
    c_out[e] = c;
    h_out[e] = h;
    if (h_out2) h_out2[e] = h;
}

// atth[e] = sum_p parts[p][e] + bh[e % H]
__global__ __launch_bounds__(256) void att_hsum(
    const float* __restrict__ parts, int nparts,
    const float* __restrict__ bh, float* __restrict__ atth)
{
    int e = blockIdx.x * 256 + threadIdx.x;   // e < B*H
    float s = bh[e & (H_ - 1)];
    for (int p = 0; p < nparts; ++p)
        s += parts[(size_t)p * B_ * H_ + e];
    atth[e] = s;
}

// scores[b,l] = sum_h tanh(p[b,l,h] + att_h[b,h]) * Wa[h] + ba
// 256 threads = 4 waves, one l per wave; float4 loads.
__global__ __launch_bounds__(256) void attn_scores(
    const float* __restrict__ p_att,
    const float* __restrict__ att_h,
    const float* __restrict__ Wa,
    const float* __restrict__ ba,
    float* __restrict__ scores)
{
    int w    = threadIdx.x >> 6;
    int lane = threadIdx.x & 63;
    int l = blockIdx.x * 4 + w;      // gridDim.x = 49
    int b = blockIdx.y;
    const float4* p   = (const float4*)(p_att + ((size_t)b * L_ + l) * H_);
    const float4* ah  = (const float4*)(att_h + (size_t)b * H_);
    const float4* wa4 = (const float4*)Wa;
    float s = 0.0f;
#pragma unroll
    for (int i = 0; i < H_ / 256; i++) {
        float4 pv = p[lane + i * 64];
        float4 av = ah[lane + i * 64];
        float4 wv = wa4[lane + i * 64];
        s += tanhf_(pv.x + av.x) * wv.x + tanhf_(pv.y + av.y) * wv.y
           + tanhf_(pv.z + av.z) * wv.z + tanhf_(pv.w + av.w) * wv.w;
    }
    for (int off = 32; off; off >>= 1) s += __shfl_down(s, off);
    if (lane == 0) scores[(size_t)b * L_ + l] = s + ba[0];
}

// w = softmax(scores, axis=1); w *= mask; w /= (sum(w)+1e-10)
__global__ __launch_bounds__(256) void attn_softmax(
    const float* __restrict__ scores, const float* __restrict__ mask,
    float* __restrict__ w)
{
    int b = blockIdx.x;
    int t = threadIdx.x;
    __shared__ float red[256];
    float v = (t < L_) ? scores[(size_t)b * L_ + t] : -1e30f;
    red[t] = v; __syncthreads();
    for (int s = 128; s; s >>= 1) {
        if (t < s) red[t] = fmaxf(red[t], red[t + s]);
        __syncthreads();
    }
    float mx = red[0]; __syncthreads();
    float e = (t < L_) ? __expf(v - mx) : 0.0f;
    red[t] = e; __syncthreads();
    for (int s = 128; s; s >>= 1) {
        if (t < s) red[t] += red[t + s];
        __syncthreads();
    }
    float denom = red[0]; __syncthreads();
    float wm = (t < L_) ? (e / denom) * mask[(size_t)b * L_ + t] : 0.0f;
    red[t] = wm; __syncthreads();
    for (int s = 128; s; s >>= 1) {
        if (t < s) red[t] += red[t + s];
        __syncthreads();
    }
    float denom2 = red[0] + 1e-10f;
    if (t < L_) w[(size_t)b * L_ + t] = wm / denom2;
}

// out[b,:] = sum_l w[b,l] * feats[b,l,:]  -- float4, one block per b.
__global__ __launch_bounds__(256) void attn_wsum(
    const float* __restrict__ w,
    const float* __restrict__ feats,
    float* __restrict__ out)
{
    int b = blockIdx.x;
    int t = threadIdx.x;                 // float4 column index, R/4 = 256
    __shared__ float ws[L_];
    if (t < L_) ws[t] = w[(size_t)b * L_ + t];
    __syncthreads();
    const float4* f = (const float4*)(feats + (size_t)b * L_ * R_) + t;
    float4 a0 = {0,0,0,0}, a1 = {0,0,0,0}, a2 = {0,0,0,0}, a3 = {0,0,0,0};
    for (int l = 0; l < L_; l += 4) {
        float4 v0 = f[(size_t)(l + 0) * 256];
        float4 v1 = f[(size_t)(l + 1) * 256];
        float4 v2 = f[(size_t)(l + 2) * 256];
        float4 v3 = f[(size_t)(l + 3) * 256];
        fma4(a0, ws[l + 0], v0);
        fma4(a1, ws[l + 1], v1);
        fma4(a2, ws[l + 2], v2);
        fma4(a3, ws[l + 3], v3);
    }
    float4 r;
    r.x = a0.x + a1.x + a2.x + a3.x;
    r.y = a0.y + a1.y + a2.y + a3.y;
    r.z = a0.z + a1.z + a2.z + a3.z;
    r.w = a0.w + a1.w + a2.w + a3.w;
    ((float4*)(out + (size_t)b * R_))[t] = r;
}

extern "C" void kernel_launch(void* const* d_in, const int* in_sizes, int n_in,
                              void* d_out, int out_size, void* d_ws, size_t ws_size,
                              hipStream_t stream)
{
    const float* xt         = (const float*)d_in[0];
    const float* fc_feats   = (const float*)d_in[1];
    const float* att_feats  = (const float*)d_in[2];
    const float* p_att      = (const float*)d_in[3];
    const float* mask       = (const float*)d_in[4];
    const float* att_feats1 = (const float*)d_in[5];
    const float* p_att1     = (const float*)d_in[6];
    const float* mask1      = (const float*)d_in[7];
    const float* state_h    = (const float*)d_in[8];
    const float* state_c    = (const float*)d_in[9];
    const float* Wih0 = (const float*)d_in[10];
    const float* Whh0 = (const float*)d_in[11];
    const float* bih0 = (const float*)d_in[12];
    const float* bhh0 = (const float*)d_in[13];
    const float* Wih1 = (const float*)d_in[14];
    const float* Whh1 = (const float*)d_in[15];
    const float* bih1 = (const float*)d_in[16];
    const float* bhh1 = (const float*)d_in[17];
    const float* WihL = (const float*)d_in[18];
    const float* WhhL = (const float*)d_in[19];
    const float* bihL = (const float*)d_in[20];
    const float* bhhL = (const float*)d_in[21];
    const float* a0_Wh = (const float*)d_in[22];
    const float* a0_bh = (const float*)d_in[23];
    const float* a0_Wa = (const float*)d_in[24];
    const float* a0_ba = (const float*)d_in[25];
    const float* a_Wh  = (const float*)d_in[26];
    const float* a_bh  = (const float*)d_in[27];
    const float* a_Wa  = (const float*)d_in[28];
    const float* a_ba  = (const float*)d_in[29];
    const float* a1_Wh = (const float*)d_in[30];
    const float* a1_bh = (const float*)d_in[31];
    const float* a1_Wa = (const float*)d_in[32];
    const float* a1_ba = (const float*)d_in[33];

    const size_t BR = (size_t)B_ * R_;
    float* out   = (float*)d_out;
    float* h0    = out + 1 * BR;
    float* h1    = out + 2 * BR;
    float* h2    = out + 3 * BR;
    float* c0    = out + 4 * BR;
    float* c1    = out + 5 * BR;
    float* c2    = out + 6 * BR;

    // ---- split-K factors (fall back if workspace too small) ----
    int KSB = 4, KSA = 4;
    {
        size_t need = ((size_t)KSB * B_ * G4R + (size_t)KSA * B_ * H_ +
                       (size_t)B_ * H_ + (size_t)B_ * L_ + 3 * BR) * sizeof(float);
        if (ws_size < need) { KSB = 1; KSA = 1; }
    }
    const int lgKSB = (KSB == 4) ? 2 : 0;
    const int lgKSA = (KSA == 4) ? 2 : 0;
    const int ntB = 128 / KSB;   // BK=32 k-tiles per block, big GEMM (K=4096)
    const int ntA = 32 / KSA;    // small GEMM (K=1024)

    float* gatesp = (float*)d_ws;                          // KSB * B*4096
    float* atthp  = gatesp + (size_t)KSB * B_ * G4R;       // KSA * B*512
    float* atth   = atthp + (size_t)KSA * B_ * H_;         // B*512
    float* sc     = atth + (size_t)B_ * H_;                // B*196
    float* att0   = sc + (size_t)B_ * L_;                  // B*1024
    float* attA   = att0 + BR;
    float* attB   = attA + BR;

    const float* prev_h = state_h + 2 * BR;

    dim3 gBig(256 * KSB);
    dim3 gAtt(128 * KSA);
    dim3 gS(49, B_);

    // ---- stage 0: LSTM att0 (x0 = [prev_h | fc | xt], h = state_h[0]) ----
    gemm_sk<64><<<gBig, 256, 0, stream>>>(
        prev_h, R_, fc_feats, 3 * R_, xt, E_, state_h, R_,
        Wih0, DIN, Wih0 + 1024, DIN, Wih0 + 2048, DIN, Whh0, R_,
        bih0, bhh0, gatesp, G4R, 2, KSB - 1, lgKSB, ntB);
    lstm_cell<<<(B_ * R_) / 256, 256, 0, stream>>>(gatesp, KSB, state_c, h0, c0, nullptr);

    // ---- attention 0 (feats1, params a0) ----
    gemm_sk<32><<<gAtt, 256, 0, stream>>>(
        h0, R_, h0, R_, h0, R_, h0, R_,
        a0_Wh, R_, a0_Wh, R_, a0_Wh, R_, a0_Wh, R_,
        nullptr, nullptr, atthp, H_, 3, KSA - 1, lgKSA, ntA);
    att_hsum<<<(B_ * H_) / 256, 256, 0, stream>>>(atthp, KSA, a0_bh, atth);
    attn_scores<<<gS, 256, 0, stream>>>(p_att1, atth, a0_Wa, a0_ba, sc);
    attn_softmax<<<B_, 256, 0, stream>>>(sc, mask1, sc);
    attn_wsum<<<B_, 256, 0, stream>>>(sc, att_feats1, att0);

    // ---- stage 1: LSTM att (x1 = [prev_h | att0 | xt], h = state_h[1]) ----
    gemm_sk<64><<<gBig, 256, 0, stream>>>(
        prev_h, R_, att0, R_, xt, E_, state_h + BR, R_,
        Wih1, DIN, Wih1 + 1024, DIN, Wih1 + 2048, DIN, Whh1, R_,
        bih1, bhh1, gatesp, G4R, 2, KSB - 1, lgKSB, ntB);
    lstm_cell<<<(B_ * R_) / 256, 256, 0, stream>>>(gatesp, KSB, state_c + BR, h1, c1, nullptr);

    // ---- attention a (feats, params a) -> attA ----
    gemm_sk<32><<<gAtt, 256, 0, stream>>>(
        h1, R_, h1, R_, h1, R_, h1, R_,
        a_Wh, R_, a_Wh, R_, a_Wh, R_, a_Wh, R_,
        nullptr, nullptr, atthp, H_, 3, KSA - 1, lgKSA, ntA);
    att_hsum<<<(B_ * H_) / 256, 256, 0, stream>>>(atthp, KSA, a_bh, atth);
    attn_scores<<<gS, 256, 0, stream>>>(p_att, atth, a_Wa, a_ba, sc);
    attn_softmax<<<B_, 256, 0, stream>>>(sc, mask, sc);
    attn_wsum<<<B_, 256, 0, stream>>>(sc, att_feats, attA);

    // ---- attention a1 (feats1, params a1) -> attB ----
    gemm_sk<32><<<gAtt, 256, 0, stream>>>(
        h1, R_, h1, R_, h1, R_, h1, R_,
        a1_Wh, R_, a1_Wh, R_, a1_Wh, R_, a1_Wh, R_,
        nullptr, nullptr, atthp, H_, 3, KSA - 1, lgKSA, ntA);
    att_hsum<<<(B_ * H_) / 256, 256, 0, stream>>>(atthp, KSA, a1_bh, atth);
    attn_scores<<<gS, 256, 0, stream>>>(p_att1, atth, a1_Wa, a1_ba, sc);
    attn_softmax<<<B_, 256, 0, stream>>>(sc, mask1, sc);
    attn_wsum<<<B_, 256, 0, stream>>>(sc, att_feats1, attB);

    // ---- stage 2: LSTM lang (xL = [attA | attB | h1], h = state_h[2]) ----
    gemm_sk<64><<<gBig, 256, 0, stream>>>(
        attA, R_, attB, R_, h1, R_, state_h + 2 * BR, R_,
        WihL, DIN, WihL + 1024, DIN, WihL + 2048, DIN, WhhL, R_,
        bihL, bhhL, gatesp, G4R, 2, KSB - 1, lgKSB, ntB);
    lstm_cell<<<(B_ * R_) / 256, 256, 0, stream>>>(gatesp, KSB, state_c + 2 * BR, h2, c2, out);
}